// Round 9
// baseline (137.875 us; speedup 1.0000x reference)
//
#include <hip/hip_runtime.h>
#include <stdint.h>

#define NBL 8
#define MBS 512   // rows per blade
#define CIN 1024  // K per blade block
#define UQ  1024  // output cols per blade

// sigma[i][k]: j such that blade_i * blade_j = sign * blade_k ; sg[i][k] = sign
__device__ __constant__ int c_sigma[8][8] = {
  {0,1,2,3,4,5,6,7},
  {1,0,4,5,2,3,7,6},
  {2,4,0,6,1,7,3,5},
  {3,5,6,0,7,1,2,4},
  {4,2,1,7,0,6,5,3},
  {5,3,7,1,6,0,4,2},
  {6,7,3,2,5,4,0,1},
  {7,6,5,4,3,2,1,0},
};
__device__ __constant__ int c_sg[8][8] = {
  { 1, 1, 1, 1, 1, 1, 1, 1},
  { 1, 1, 1, 1, 1, 1, 1, 1},
  { 1,-1, 1, 1,-1,-1, 1,-1},
  { 1,-1,-1, 1, 1,-1,-1, 1},
  {-1, 1,-1,-1, 1, 1,-1, 1},
  {-1, 1, 1,-1,-1, 1, 1,-1},
  {-1,-1, 1,-1, 1,-1, 1, 1},
  {-1,-1, 1,-1, 1,-1, 1, 1},
};

typedef short bf16x8 __attribute__((ext_vector_type(8)));
typedef float f32x4 __attribute__((ext_vector_type(4)));

__device__ __forceinline__ uint32_t f2bf(float f) {
  uint32_t u = __float_as_uint(f);
  return (u + 0x7fffu + ((u >> 16) & 1u)) >> 16;  // RNE
}
__device__ __forceinline__ uint32_t pk2(float lo, float hi) {
  return f2bf(lo) | (f2bf(hi) << 16);
}

// ---------------- prepass: blocked workspace layouts ----------------
// X'[i][chunk c 0..127][row m 0..511][8 elems]  (+ and - sign copies)
// W'[j][chunk c 0..127][col u 0..1023][8 elems]
// chunk c covers k = c*8..c*8+7 within the blade's K=1024.

__global__ void cvt_x_kernel(const float* __restrict__ x,
                             uint4* __restrict__ xp, uint4* __restrict__ xn) {
  __shared__ uint4 t16[32 * 33];
  const int tid = threadIdx.x;           // 256
  const int tx = tid & 31, ty = tid >> 5;
  const int i  = blockIdx.x >> 2;        // blade 0..7
  const int cb = blockIdx.x & 3;         // chunk-block 0..3
  const int m0 = blockIdx.y * 32;        // row-block
#pragma unroll
  for (int r = 0; r < 4; ++r) {
    const int m = m0 + ty + r * 8;
    const float* src = x + ((size_t)(i * MBS + m)) * CIN + cb * 256 + tx * 8;
    float4 a = *(const float4*)src;
    float4 b = *(const float4*)(src + 4);
    uint4 p;
    p.x = pk2(a.x, a.y); p.y = pk2(a.z, a.w);
    p.z = pk2(b.x, b.y); p.w = pk2(b.z, b.w);
    t16[tx * 33 + ty + r * 8] = p;
  }
  __syncthreads();
#pragma unroll
  for (int p = 0; p < 4; ++p) {
    const int slot = p * 256 + tid;
    const int cc = slot >> 5, mm = slot & 31;
    uint4 v = t16[cc * 33 + mm];
    const size_t o = (size_t)(i * 128 + cb * 32 + cc) * 512 + m0 + mm;
    xp[o] = v;
    uint4 n;
    n.x = v.x ^ 0x80008000u; n.y = v.y ^ 0x80008000u;
    n.z = v.z ^ 0x80008000u; n.w = v.w ^ 0x80008000u;
    xn[o] = n;
  }
}

__global__ void cvt_w_kernel(const float* __restrict__ w, uint4* __restrict__ wp) {
  __shared__ float tile[32][65];
  const int tid = threadIdx.x;  // 256
  const int tx = tid & 63, ty = tid >> 6;
  const int n0 = blockIdx.x * 64;
  const int k0 = blockIdx.y * 32;
#pragma unroll
  for (int r = 0; r < 8; ++r) {
    const int kr = ty * 8 + r;
    tile[kr][tx] = w[(size_t)(k0 + kr) * 8192 + n0 + tx];
  }
  __syncthreads();
  {
    const int cc = tid >> 6;
    const int uu = tid & 63;
    const int nn = n0 + uu;
    const int j = nn >> 10;
    const int col = nn & 1023;
    uint4 v;
    v.x = pk2(tile[cc * 8 + 0][uu], tile[cc * 8 + 1][uu]);
    v.y = pk2(tile[cc * 8 + 2][uu], tile[cc * 8 + 3][uu]);
    v.z = pk2(tile[cc * 8 + 4][uu], tile[cc * 8 + 5][uu]);
    v.w = pk2(tile[cc * 8 + 6][uu], tile[cc * 8 + 7][uu]);
    wp[(size_t)(j * 128 + blockIdx.y * 4 + cc) * 1024 + col] = v;
  }
}

__global__ void bias_fill(const float* __restrict__ bias, float4* __restrict__ out) {
  int idx = blockIdx.x * 256 + threadIdx.x;
  int row = idx >> 8;
  int c4 = idx & 255;
  int k = row >> 9;
  out[idx] = ((const float4*)(bias + k * UQ))[c4];
}

#define BAR() do { asm volatile("s_barrier" ::: "memory");                    \
                   __builtin_amdgcn_sched_barrier(0); } while (0)
#define VMW(N) asm volatile("s_waitcnt vmcnt(" #N ")" ::: "memory")

// ---- 256x256x(BK=32) GEMM, 4 waves of 128x128 (64 FLOP/LDS-byte), ----
// split-K=4 (grid 256 = 1 block/CU), ring-4 LDS (stage depth 3), frag
// read-ahead depth 1: iter t = VMW(8); BAR; issue READ(t+1)+STAGE(t+3);
// sched_barrier; 64 MFMA(t) on pre-read frags. LDS delivery (~750-1130
// cyc/CU) hides under MFMA (1241 cyc/CU). vmcnt ledger: 8 outstanding
// steady (2 stages in flight); VMW(8) proves stage(t+1) landed (issued
// 2 iters back). Ring reuse: stage(t+3) hits ring[(t-1)%4], dead since
// MFMA(t-1) consumed it before iter-t's barrier.

#define READ_FRAGS(FA, FB, R)                                                 \
  _Pragma("unroll")                                                           \
  for (int f = 0; f < 8; ++f)                                                 \
    FA[f] = *(const bf16x8*)(lds + (R) * 16384 +                              \
        (hi * 256 + wr * 128 + f * 16 + r15) * 8);                            \
  _Pragma("unroll")                                                           \
  for (int g = 0; g < 8; ++g)                                                 \
    FB[g] = *(const bf16x8*)(lds + (R) * 16384 + 8192 +                       \
        (hi * 256 + wc * 128 + g * 16 + r15) * 8);

#define STAGE(G, R) {                                                         \
  const int g_ = (G);                                                         \
  const int c0_ = (g_ & 31) << 2;                                             \
  const uint16_t* pa_ = (g_ & 32) ? paI1 : paI0;                              \
  const uint16_t* pb_ = (g_ & 32) ? pbI1 : pbI0;                              \
  _Pragma("unroll")                                                           \
  for (int n = 0; n < 4; ++n) {                                               \
    __builtin_amdgcn_global_load_lds(                                         \
        (const __attribute__((address_space(1))) uint32_t*)                   \
            (pa_ + ((size_t)(c0_ + n) * 512 + mt * 256 + tid) * 8),           \
        (__attribute__((address_space(3))) uint32_t*)                         \
            (lds + (R) * 16384 + (n * 256 + tid) * 8), 16, 0, 0);             \
    __builtin_amdgcn_global_load_lds(                                         \
        (const __attribute__((address_space(1))) uint32_t*)                   \
            (pb_ + ((size_t)(c0_ + n) * 1024 + ut * 256 + tid) * 8),          \
        (__attribute__((address_space(3))) uint32_t*)                         \
            (lds + (R) * 16384 + 8192 + (n * 256 + tid) * 8), 16, 0, 0);      \
  }                                                                           \
}

#define MFMA64(FA, FB)                                                        \
  __builtin_amdgcn_s_setprio(1);                                              \
  _Pragma("unroll")                                                           \
  for (int f = 0; f < 8; ++f)                                                 \
    _Pragma("unroll")                                                         \
    for (int g = 0; g < 8; ++g)                                               \
      acc[f][g] = __builtin_amdgcn_mfma_f32_16x16x32_bf16(                    \
          FA[f], FB[g], acc[f][g], 0, 0, 0);                                  \
  __builtin_amdgcn_s_setprio(0);

#define ITER(T, RNXT, RSTG, CA, CB, LA, LB) {                                 \
  VMW(8);                                                                     \
  BAR();                                                                      \
  const int gt_ = ((T) + 3 < 64) ? (T) + 3 : 63;                              \
  READ_FRAGS(LA, LB, RNXT);                                                   \
  STAGE(gt_, RSTG);                                                           \
  __builtin_amdgcn_sched_barrier(0);                                          \
  MFMA64(CA, CB);                                                             \
}

__global__ __launch_bounds__(256, 1) void ga_w128(
    const uint16_t* __restrict__ xp, const uint16_t* __restrict__ xn,
    const uint16_t* __restrict__ wp, float* __restrict__ out) {
  extern __shared__ uint16_t lds[];  // ring-4 x [A 16KB | B 16KB] = 128 KB

  const int tid  = threadIdx.x;
  const int bid  = blockIdx.x;
  const int s    = bid >> 6;          // K-split 0..3 (2 i-blocks each)
  const int k    = (bid >> 3) & 7;    // blade
  const int mt   = (bid >> 2) & 1;    // m-tile (256 rows)
  const int ut   = bid & 3;           // n-tile (256 cols)
  const int lane = tid & 63;
  const int wid  = tid >> 6;          // 0..3
  const int wr   = wid >> 1;          // 0..1 (128-row slice)
  const int wc   = wid & 1;           // 0..1 (128-col slice)
  const int r15  = lane & 15, hi = lane >> 4;

  const int i0 = s * 2, i1 = s * 2 + 1;
  const uint16_t* paI0 = (c_sg[i0][k] > 0 ? xp : xn) + (size_t)i0 * 524288;
  const uint16_t* paI1 = (c_sg[i1][k] > 0 ? xp : xn) + (size_t)i1 * 524288;
  const uint16_t* pbI0 = wp + (size_t)c_sigma[i0][k] * 1048576;
  const uint16_t* pbI1 = wp + (size_t)c_sigma[i1][k] * 1048576;

  f32x4 acc[8][8];
  const f32x4 z = {0.f, 0.f, 0.f, 0.f};
#pragma unroll
  for (int a = 0; a < 8; ++a)
#pragma unroll
    for (int b = 0; b < 8; ++b) acc[a][b] = z;

  bf16x8 fEa[8], fEb[8], fOa[8], fOb[8];

  // prologue: stage steps 0,1,2 into rings 0,1,2; prove step 0 landed;
  // pre-read frags(0) into E-set.
  STAGE(0, 0); STAGE(1, 1); STAGE(2, 2);
  VMW(16);
  BAR();
  READ_FRAGS(fEa, fEb, 0);

  for (int tq = 0; tq < 64; tq += 4) {
    ITER(tq + 0, 1, 3, fEa, fEb, fOa, fOb);
    ITER(tq + 1, 2, 0, fOa, fOb, fEa, fEb);
    ITER(tq + 2, 3, 1, fEa, fEb, fOa, fOb);
    ITER(tq + 3, 0, 2, fOa, fOb, fEa, fEb);
  }

  // epilogue: atomic accumulate (D: col = lane&15, row = (lane>>4)*4 + r)
  const int row0 = k * MBS + mt * 256 + wr * 128;
  const int col0 = ut * 256 + wc * 128;
#pragma unroll
  for (int g = 0; g < 8; ++g) {
    const int col = col0 + g * 16 + r15;
#pragma unroll
    for (int f = 0; f < 8; ++f) {
      const int r0 = row0 + f * 16 + hi * 4;
#pragma unroll
      for (int r = 0; r < 4; ++r)
        unsafeAtomicAdd(&out[(size_t)(r0 + r) * UQ + col], acc[f][g][r]);
    }
  }
}

// Fallback (ws too small): correct fp32 path, slow.
__global__ void ga_naive(const float* __restrict__ x, const float* __restrict__ w,
                         const float* __restrict__ bias, float* __restrict__ out) {
  int col = blockIdx.x * 256 + threadIdx.x;
  int row = blockIdx.y;
  int k = row >> 9, m = row & 511;
  float acc = bias[k * UQ + col];
  for (int i = 0; i < 8; ++i) {
    int j = c_sigma[i][k];
    float s = (float)c_sg[i][k];
    const float* xr = x + (size_t)(i * MBS + m) * CIN;
    const float* wc = w + (size_t)j * UQ + col;
    float a = 0.f;
    for (int c = 0; c < CIN; ++c) a = fmaf(xr[c], wc[(size_t)c * (NBL * UQ)], a);
    acc = fmaf(s, a, acc);
  }
  out[(size_t)row * UQ + col] = acc;
}

extern "C" void kernel_launch(void* const* d_in, const int* in_sizes, int n_in,
                              void* d_out, int out_size, void* d_ws, size_t ws_size,
                              hipStream_t stream) {
  const float* x    = (const float*)d_in[0];   // 4096*1024
  const float* W    = (const float*)d_in[1];   // 1024*8192
  const float* bias = (const float*)d_in[2];   // 8192
  float* out = (float*)d_out;                  // 4096*1024

  const size_t need = 32u * 1024u * 1024u;     // Xp' 8MB, Xn' 8MB, W' 16MB
  if (ws_size < need) {
    ga_naive<<<dim3(4, 4096), dim3(256), 0, stream>>>(x, W, bias, out);
    return;
  }

  uint16_t* xp = (uint16_t*)d_ws;
  uint16_t* xn = xp + 4194304;
  uint16_t* wp = xn + 4194304;

  cvt_x_kernel<<<dim3(32, 16), dim3(256), 0, stream>>>(x, (uint4*)xp, (uint4*)xn);
  cvt_w_kernel<<<dim3(128, 32), dim3(256), 0, stream>>>(W, (uint4*)wp);
  bias_fill<<<dim3(4096), dim3(256), 0, stream>>>(bias, (float4*)out);
  ga_w128<<<dim3(256), dim3(256), 131072, stream>>>(xp, xn, wp, out);
}

// Round 10
// 103.778 us; speedup vs baseline: 1.3286x; 1.3286x over previous
//
#include <hip/hip_runtime.h>
#include <stdint.h>

#define NBL 8
#define MBS 512   // rows per blade
#define CIN 1024  // K per blade block
#define UQ  1024  // output cols per blade

// sigma[i][k]: j such that blade_i * blade_j = sign * blade_k ; sg[i][k] = sign
__device__ __constant__ int c_sigma[8][8] = {
  {0,1,2,3,4,5,6,7},
  {1,0,4,5,2,3,7,6},
  {2,4,0,6,1,7,3,5},
  {3,5,6,0,7,1,2,4},
  {4,2,1,7,0,6,5,3},
  {5,3,7,1,6,0,4,2},
  {6,7,3,2,5,4,0,1},
  {7,6,5,4,3,2,1,0},
};
__device__ __constant__ int c_sg[8][8] = {
  { 1, 1, 1, 1, 1, 1, 1, 1},
  { 1, 1, 1, 1, 1, 1, 1, 1},
  { 1,-1, 1, 1,-1,-1, 1,-1},
  { 1,-1,-1, 1, 1,-1,-1, 1},
  {-1, 1,-1,-1, 1, 1,-1, 1},
  {-1, 1, 1,-1,-1, 1, 1,-1},
  {-1,-1, 1,-1, 1,-1, 1, 1},
  {-1,-1, 1,-1, 1,-1, 1, 1},
};

typedef short bf16x8 __attribute__((ext_vector_type(8)));
typedef float f32x4 __attribute__((ext_vector_type(4)));

__device__ __forceinline__ uint32_t f2bf(float f) {
  uint32_t u = __float_as_uint(f);
  return (u + 0x7fffu + ((u >> 16) & 1u)) >> 16;  // RNE
}
__device__ __forceinline__ uint32_t pk2(float lo, float hi) {
  return f2bf(lo) | (f2bf(hi) << 16);
}

// ---------------- prepass: blocked workspace layouts ----------------
// X'[i][chunk c 0..127][row m 0..511][8 elems]  (+ and - sign copies)
// W'[j][chunk c 0..127][col u 0..1023][8 elems]
// chunk c covers k = c*8..c*8+7 within the blade's K=1024.

__global__ void cvt_x_kernel(const float* __restrict__ x,
                             uint4* __restrict__ xp, uint4* __restrict__ xn) {
  __shared__ uint4 t16[32 * 33];
  const int tid = threadIdx.x;           // 256
  const int tx = tid & 31, ty = tid >> 5;
  const int i  = blockIdx.x >> 2;        // blade 0..7
  const int cb = blockIdx.x & 3;         // chunk-block 0..3
  const int m0 = blockIdx.y * 32;        // row-block
#pragma unroll
  for (int r = 0; r < 4; ++r) {
    const int m = m0 + ty + r * 8;
    const float* src = x + ((size_t)(i * MBS + m)) * CIN + cb * 256 + tx * 8;
    float4 a = *(const float4*)src;
    float4 b = *(const float4*)(src + 4);
    uint4 p;
    p.x = pk2(a.x, a.y); p.y = pk2(a.z, a.w);
    p.z = pk2(b.x, b.y); p.w = pk2(b.z, b.w);
    t16[tx * 33 + ty + r * 8] = p;
  }
  __syncthreads();
#pragma unroll
  for (int p = 0; p < 4; ++p) {
    const int slot = p * 256 + tid;
    const int cc = slot >> 5, mm = slot & 31;
    uint4 v = t16[cc * 33 + mm];
    const size_t o = (size_t)(i * 128 + cb * 32 + cc) * 512 + m0 + mm;
    xp[o] = v;
    uint4 n;
    n.x = v.x ^ 0x80008000u; n.y = v.y ^ 0x80008000u;
    n.z = v.z ^ 0x80008000u; n.w = v.w ^ 0x80008000u;
    xn[o] = n;
  }
}

__global__ void cvt_w_kernel(const float* __restrict__ w, uint4* __restrict__ wp) {
  __shared__ float tile[32][65];
  const int tid = threadIdx.x;  // 256
  const int tx = tid & 63, ty = tid >> 6;
  const int n0 = blockIdx.x * 64;
  const int k0 = blockIdx.y * 32;
#pragma unroll
  for (int r = 0; r < 8; ++r) {
    const int kr = ty * 8 + r;
    tile[kr][tx] = w[(size_t)(k0 + kr) * 8192 + n0 + tx];
  }
  __syncthreads();
  {
    const int cc = tid >> 6;
    const int uu = tid & 63;
    const int nn = n0 + uu;
    const int j = nn >> 10;
    const int col = nn & 1023;
    uint4 v;
    v.x = pk2(tile[cc * 8 + 0][uu], tile[cc * 8 + 1][uu]);
    v.y = pk2(tile[cc * 8 + 2][uu], tile[cc * 8 + 3][uu]);
    v.z = pk2(tile[cc * 8 + 4][uu], tile[cc * 8 + 5][uu]);
    v.w = pk2(tile[cc * 8 + 6][uu], tile[cc * 8 + 7][uu]);
    wp[(size_t)(j * 128 + blockIdx.y * 4 + cc) * 1024 + col] = v;
  }
}

__global__ void bias_fill(const float* __restrict__ bias, float4* __restrict__ out) {
  int idx = blockIdx.x * 256 + threadIdx.x;
  int row = idx >> 8;
  int c4 = idx & 255;
  int k = row >> 9;
  out[idx] = ((const float4*)(bias + k * UQ))[c4];
}

#define BAR() do { asm volatile("s_barrier" ::: "memory");                    \
                   __builtin_amdgcn_sched_barrier(0); } while (0)
#define VMW(N) asm volatile("s_waitcnt vmcnt(" #N ")" ::: "memory")

// ---- 128x128x(BK=32) ring-4 GEMM, split-K=2, 2 blocks/CU ----
// R6 base + cross-iteration FRAGMENT DOUBLE-BUFFER: iter t reads frags(t+1)
// (8 ds_read_b128) BEFORE the 16 MFMA(t); sched_barrier(0) pins the order;
// compiler emits lgkmcnt(8) before MFMA (waits only on LAST iter's reads,
// which are long done) so this iter's reads retire UNDER the MFMAs.
// vmcnt ledger (4 loads/stage, in-order retire): VMW(4) at iter top forces
// stage(t+1) landed (only stage(t+2) in flight); VMW before BAR makes all
// waves' staging visible before any wave's ds_read. stage(t+3) overwrites
// ring[(t-1)&3], whose reads finished before this iter's BAR. Tail clamps
// re-stage step 127 with identical bytes (benign).
__global__ __launch_bounds__(256, 2) void ga_ring2(
    const uint16_t* __restrict__ xp, const uint16_t* __restrict__ xn,
    const uint16_t* __restrict__ wp, float* __restrict__ out) {
  __shared__ uint16_t lds[4][8192];  // ring: [buf][A 4096 | B 4096] u16 = 64 KB

  const int tid  = threadIdx.x;
  const int bid  = blockIdx.x;
  const int s    = bid >> 8;          // K-split 0/1 (4 i-blocks each)
  const int k    = (bid >> 5) & 7;
  const int mt   = (bid >> 3) & 3;
  const int ut   = bid & 7;
  const int lane = tid & 63;
  const int wid  = tid >> 6;
  const int wr   = wid >> 1, wc = wid & 1;  // 2x2 waves, each 64x64 out
  const int r15  = lane & 15, hi = lane >> 4;

  uint32_t sig_pack = 0, pos_pack = 0;
#pragma unroll
  for (int ib = 0; ib < 4; ++ib) {
    sig_pack |= (uint32_t)c_sigma[s * 4 + ib][k] << (4 * ib);
    pos_pack |= (uint32_t)(c_sg[s * 4 + ib][k] > 0) << ib;
  }
  const int hc = tid >> 7;                     // 0/1 within a stage call
  const size_t mrow8 = (size_t)(mt * 128 + (tid & 127)) * 8;
  const size_t urow8 = (size_t)(ut * 128 + (tid & 127)) * 8;

  f32x4 acc[4][4];
  const f32x4 z = {0.f, 0.f, 0.f, 0.f};
#pragma unroll
  for (int a = 0; a < 4; ++a)
#pragma unroll
    for (int b = 0; b < 4; ++b) acc[a][b] = z;

  // stage step u (BK=32 = 4 chunks): 2 A-loads + 2 B-loads per thread
  auto stage = [&](int u) {
    const int ib = u >> 5;
    const int c0 = (u & 31) << 2;
    const int j  = (sig_pack >> (4 * ib)) & 15;
    const uint16_t* xb = ((pos_pack >> ib) & 1) ? xp : xn;
    const size_t abase = ((size_t)(s * 4 + ib) << 19);
    const size_t bbase = ((size_t)j << 20);
    uint16_t* la = lds[u & 3];
    uint16_t* lb = lds[u & 3] + 4096;
#pragma unroll
    for (int u2 = 0; u2 < 2; ++u2) {
      const int cc = c0 + u2 * 2 + hc;
      __builtin_amdgcn_global_load_lds(
          (const __attribute__((address_space(1))) uint32_t*)(xb + abase + (size_t)cc * 4096 + mrow8),
          (__attribute__((address_space(3))) uint32_t*)(la + (u2 * 256 + tid) * 8), 16, 0, 0);
      __builtin_amdgcn_global_load_lds(
          (const __attribute__((address_space(1))) uint32_t*)(wp + bbase + (size_t)cc * 8192 + urow8),
          (__attribute__((address_space(3))) uint32_t*)(lb + (u2 * 256 + tid) * 8), 16, 0, 0);
    }
  };

#define READF(FA, FB, RB) {                                                   \
  const uint16_t* b_ = lds[(RB)];                                             \
  _Pragma("unroll")                                                           \
  for (int f = 0; f < 4; ++f)                                                 \
    FA[f] = *(const bf16x8*)(b_ + ((hi << 7) + wr * 64 + f * 16 + r15) * 8);  \
  _Pragma("unroll")                                                           \
  for (int g = 0; g < 4; ++g)                                                 \
    FB[g] = *(const bf16x8*)(b_ + 4096 + ((hi << 7) + wc * 64 + g * 16 + r15) * 8); \
}

#define ITER(T, CA, CB, LA, LB) {                                             \
  VMW(4);                                                                     \
  BAR();                                                                      \
  stage(((T) + 3 < 127) ? (T) + 3 : 127);                                     \
  READF(LA, LB, ((((T) + 1 < 127) ? (T) + 1 : 127) & 3));                     \
  __builtin_amdgcn_sched_barrier(0);                                          \
  __builtin_amdgcn_s_setprio(1);                                              \
  _Pragma("unroll")                                                           \
  for (int f = 0; f < 4; ++f)                                                 \
    _Pragma("unroll")                                                         \
    for (int g = 0; g < 4; ++g)                                               \
      acc[f][g] = __builtin_amdgcn_mfma_f32_16x16x32_bf16(                    \
          CA[f], CB[g], acc[f][g], 0, 0, 0);                                  \
  __builtin_amdgcn_s_setprio(0);                                              \
}

  bf16x8 fCa[4], fCb[4], fNa[4], fNb[4];

  // prologue: 3 stages in flight; prove 0,1 landed; pre-read frags(0)
  stage(0); stage(1); stage(2);
  VMW(4);
  BAR();
  READF(fCa, fCb, 0);

  for (int t = 0; t < 128; t += 2) {
    ITER(t,     fCa, fCb, fNa, fNb);
    ITER(t + 1, fNa, fNb, fCa, fCb);
  }

  // epilogue: atomic accumulate (D: col = lane&15, row = (lane>>4)*4 + r)
  const int row0 = k * MBS + mt * 128 + wr * 64;
  const int col0 = ut * 128 + wc * 64;
#pragma unroll
  for (int g = 0; g < 4; ++g) {
    const int col = col0 + g * 16 + r15;
#pragma unroll
    for (int f = 0; f < 4; ++f) {
      const int r0 = row0 + f * 16 + hi * 4;
#pragma unroll
      for (int r = 0; r < 4; ++r)
        unsafeAtomicAdd(&out[(size_t)(r0 + r) * UQ + col], acc[f][g][r]);
    }
  }
}

// Fallback (ws too small): correct fp32 path, slow.
__global__ void ga_naive(const float* __restrict__ x, const float* __restrict__ w,
                         const float* __restrict__ bias, float* __restrict__ out) {
  int col = blockIdx.x * 256 + threadIdx.x;
  int row = blockIdx.y;
  int k = row >> 9, m = row & 511;
  float acc = bias[k * UQ + col];
  for (int i = 0; i < 8; ++i) {
    int j = c_sigma[i][k];
    float s = (float)c_sg[i][k];
    const float* xr = x + (size_t)(i * MBS + m) * CIN;
    const float* wc = w + (size_t)j * UQ + col;
    float a = 0.f;
    for (int c = 0; c < CIN; ++c) a = fmaf(xr[c], wc[(size_t)c * (NBL * UQ)], a);
    acc = fmaf(s, a, acc);
  }
  out[(size_t)row * UQ + col] = acc;
}

extern "C" void kernel_launch(void* const* d_in, const int* in_sizes, int n_in,
                              void* d_out, int out_size, void* d_ws, size_t ws_size,
                              hipStream_t stream) {
  const float* x    = (const float*)d_in[0];   // 4096*1024
  const float* W    = (const float*)d_in[1];   // 1024*8192
  const float* bias = (const float*)d_in[2];   // 8192
  float* out = (float*)d_out;                  // 4096*1024

  const size_t need = 32u * 1024u * 1024u;     // Xp' 8MB, Xn' 8MB, W' 16MB
  if (ws_size < need) {
    ga_naive<<<dim3(4, 4096), dim3(256), 0, stream>>>(x, W, bias, out);
    return;
  }

  uint16_t* xp = (uint16_t*)d_ws;
  uint16_t* xn = xp + 4194304;
  uint16_t* wp = xn + 4194304;

  cvt_x_kernel<<<dim3(32, 16), dim3(256), 0, stream>>>(x, (uint4*)xp, (uint4*)xn);
  cvt_w_kernel<<<dim3(128, 32), dim3(256), 0, stream>>>(W, (uint4*)wp);
  bias_fill<<<dim3(4096), dim3(256), 0, stream>>>(bias, (float4*)out);
  ga_ring2<<<dim3(512), dim3(256), 0, stream>>>(xp, xn, wp, out);
}